// Round 10
// baseline (1028.142 us; speedup 1.0000x reference)
//
#include <hip/hip_runtime.h>
#include <math.h>

typedef unsigned short u16;
typedef unsigned int u32;
typedef __bf16 bf16x8 __attribute__((ext_vector_type(8)));
typedef float f32x4 __attribute__((ext_vector_type(4)));
typedef u16 us8 __attribute__((ext_vector_type(8)));

#define TOKENS 1024
#define DIM 256
#define SEQ 512

// ---------- helpers ----------

__device__ __forceinline__ u16 f2bf(float f) {
  u32 x = __float_as_uint(f);
  x += 0x7fffu + ((x >> 16) & 1u);
  return (u16)(x >> 16);
}

// silu + 8 cubic B-spline bases, uniform extended grid g[j] = (j-3)*0.4f - 1.0f.
// Compile-time-reciprocal Cox-de Boor (denominators constant).
__device__ __forceinline__ void expand9(float x, u16* sil, us8* u) {
  float sig = 1.0f / (1.0f + expf(-x));
  *sil = f2bf(x * sig);
  float bs[11];
#pragma unroll
  for (int j = 0; j < 11; j++) {
    float gj  = (float)(j - 3) * 0.4f - 1.0f;
    float gj1 = (float)(j - 2) * 0.4f - 1.0f;
    bs[j] = (x >= gj && x < gj1) ? 1.0f : 0.0f;
  }
#pragma unroll
  for (int k = 1; k <= 3; k++) {
#pragma unroll
    for (int j = 0; j < 10; j++) {
      if (j + k < 11) {
        float gj   = (float)(j - 3) * 0.4f - 1.0f;
        float gj1  = (float)(j - 2) * 0.4f - 1.0f;
        float gjk  = (float)(j + k - 3) * 0.4f - 1.0f;
        float gjk1 = (float)(j + k - 2) * 0.4f - 1.0f;
        float linv = 1.0f / (gjk - gj);
        float rinv = 1.0f / (gjk1 - gj1);
        bs[j] = (x - gj) * linv * bs[j] + (gjk1 - x) * rinv * bs[j + 1];
      }
    }
  }
#pragma unroll
  for (int c = 0; c < 8; c++) (*u)[c] = f2bf(bs[c]);
}

// 256-thread block sum (4 waves of 64)
__device__ __forceinline__ float block_sum_256(float v) {
  __shared__ float red[4];
  int t = threadIdx.x, lane = t & 63, wid = t >> 6;
#pragma unroll
  for (int o = 32; o > 0; o >>= 1) v += __shfl_down(v, o, 64);
  __syncthreads();
  if (lane == 0) red[wid] = v;
  __syncthreads();
  return red[0] + red[1] + red[2] + red[3];
}

// ---------- embedding + LN (eps 1e-12) + expand ----------

__global__ void embed_ln_x(const int* __restrict__ ids, const float* __restrict__ wemb,
                           const float* __restrict__ tt, const float* __restrict__ pe,
                           const float* __restrict__ g, const float* __restrict__ bta,
                           float* __restrict__ xout, u16* __restrict__ Xe) {
  int row = blockIdx.x, t = threadIdx.x;
  int id = ids[row];
  float v = wemb[(size_t)id * DIM + t] + tt[DIM + t] + pe[DIM + t];
  float mu = block_sum_256(v) * (1.0f / 256.0f);
  float d = v - mu;
  float var = block_sum_256(d * d) * (1.0f / 256.0f);
  float y = d * rsqrtf(var + 1e-12f) * g[t] + bta[t];
  xout[(size_t)row * DIM + t] = y;
  size_t base = (size_t)row * 2304;
  u16 s; us8 u;
  expand9(y, &s, &u);
  Xe[base + t] = s;
  *(us8*)(Xe + base + 256 + (size_t)t * 8) = u;
}

// ---------- (sum of nsum partials) [+gelu] [+res] + LN + expand ----------

__global__ void add_ln_x(const float* __restrict__ a, int nsum, int sstride,
                         const float* __restrict__ res,
                         const float* __restrict__ g, const float* __restrict__ bta,
                         float eps, int dogelu,
                         float* __restrict__ xout, u16* __restrict__ Xe) {
  int row = blockIdx.x, t = threadIdx.x;
  int idx = row * 256 + t;
  float v = 0.f;
  for (int s = 0; s < nsum; s++) v += a[(size_t)s * sstride + idx];
  if (dogelu) v = 0.5f * v * (1.0f + erff(v * 0.70710678118654752f));
  if (res) v += res[idx];
  float mu = block_sum_256(v) * (1.0f / 256.0f);
  float d = v - mu;
  float var = block_sum_256(d * d) * (1.0f / 256.0f);
  float y = d * rsqrtf(var + eps);
  if (g) y = y * g[t] + bta[t];
  xout[idx] = y;
  size_t base = (size_t)row * 2304;
  u16 s16; us8 u;
  expand9(y, &s16, &u);
  Xe[base + t] = s16;
  *(us8*)(Xe + base + 256 + (size_t)t * 8) = u;
}

// ---------- sum Z split-K partials of qkv: [Z][1024*768] -> [1024*768] ----------

__global__ void qkv_sum(const float* __restrict__ p, float* __restrict__ o, int z) {
  int i4 = (blockIdx.x * 256 + threadIdx.x) * 4;
  float4 acc = *(const float4*)(p + i4);
  for (int s = 1; s < z; s++) {
    float4 v = *(const float4*)(p + (size_t)s * TOKENS * 768 + i4);
    acc.x += v.x; acc.y += v.y; acc.z += v.z; acc.w += v.w;
  }
  *(float4*)(o + i4) = acc;
}

// ---------- sum Z partials + relu + expand: ff1p[Z][1024*1024] -> Xe2[1024,9216] ----------

__global__ void expand_ff(const float* __restrict__ X, u16* __restrict__ Xe, int z) {
  int idx = blockIdx.x * 256 + threadIdx.x;
  int n = idx >> 10, i = idx & 1023;
  float x = X[idx];
  for (int s = 1; s < z; s++) x += X[(size_t)s * TOKENS * 1024 + idx];
  x = fmaxf(x, 0.0f);
  u16 s16; us8 u;
  expand9(x, &s16, &u);
  size_t base = (size_t)n * 9216;
  Xe[base + i] = s16;
  *(us8*)(Xe + base + 1024 + (size_t)i * 8) = u;
}

// ---------- GEMM: C[1024,N] = A[1024,K](bf16) @ Wvirt[N,K]^T, W = [base|spline] f32 ----------
// f32 weights converted RNE->bf16 during staging. XCD-contiguous remap, XOR-swizzled
// LDS, named-register prefetch pipeline. blockIdx.z = K-split slice (kchunk, multiple
// of BK); partial C at z*TOKENS*N.

#define LDA4(c, v) { int r_ = (c) * RPC + (t >> LGP); int g_ = t & (GPB - 1); \
    v = *(const uint4*)(A + (size_t)(m0 + r_) * K + k0n + g_ * 8); }
#define LDB4(c, va, vb) { int r_ = (c) * RPC + (t >> LGP); int g_ = t & (GPB - 1); \
    int kv_ = k0n + g_ * 8; \
    const float* p_ = (kv_ < infeat) ? (Wb + (size_t)(onb + r_) * infeat + kv_) \
                                     : (Ws + (size_t)(onb + r_) * infeat * 8 + (kv_ - infeat)); \
    va = *(const float4*)p_; vb = *(const float4*)(p_ + 4); }
#define STA4(c, v) { int r_ = (c) * RPC + (t >> LGP); int g_ = t & (GPB - 1); \
    *(uint4*)(&As[r_ * BK + ((g_ ^ (r_ & (GPB - 1))) << 3)]) = v; }
#define STB4(c, va, vb) { int r_ = (c) * RPC + (t >> LGP); int g_ = t & (GPB - 1); \
    bf16x8 h_; \
    h_[0] = (__bf16)va.x; h_[1] = (__bf16)va.y; h_[2] = (__bf16)va.z; h_[3] = (__bf16)va.w; \
    h_[4] = (__bf16)vb.x; h_[5] = (__bf16)vb.y; h_[6] = (__bf16)vb.z; h_[7] = (__bf16)vb.w; \
    *(bf16x8*)(&Bs[r_ * BK + ((g_ ^ (r_ & (GPB - 1))) << 3)]) = h_; }

template <int BM, int BN, int BK, int MINW>
__global__ __launch_bounds__(256, MINW)
void gemm_kw(const u16* __restrict__ A,
             const float* __restrict__ b0, const float* __restrict__ s0,
             const float* __restrict__ b1, const float* __restrict__ s1,
             const float* __restrict__ b2, const float* __restrict__ s2,
             int nper, int N, int K, int infeat, int kchunk, float* __restrict__ C) {
  constexpr int GPB = BK / 8;                // 8-col groups per row
  constexpr int LGP = (GPB == 8) ? 3 : 4;
  constexpr int RPC = 256 / GPB;             // rows per staging chunk
  static_assert(BM / RPC == 4 && BN / RPC == 4, "need exactly 4+4 chunks");
  constexpr int FM = BM / 32, FN = BN / 32;
  __shared__ u16 As[BM * BK];
  __shared__ u16 Bs[BN * BK];
  const int gx = gridDim.x;
  const int nwg = gx * gridDim.y;
  int g = blockIdx.y * gx + blockIdx.x;
  int lin = g;
  if ((nwg & 7) == 0) lin = (g & 7) * (nwg >> 3) + (g >> 3);
  const int m0 = (lin % gx) * BM;
  const int n0 = (lin / gx) * BN;
  const int z = blockIdx.z;
  const int kbeg = z * kchunk;
  const int kend = (kbeg + kchunk < K) ? kbeg + kchunk : K;
  const int t = threadIdx.x;
  const int lane = t & 63, wid = t >> 6;
  const int wm = (wid >> 1) * (BM / 2), wn = (wid & 1) * (BN / 2);
  const int proj = n0 / nper;
  const float* Wb = proj == 0 ? b0 : (proj == 1 ? b1 : b2);
  const float* Ws = proj == 0 ? s0 : (proj == 1 ? s1 : s2);
  const int onb = n0 - proj * nper;

  f32x4 acc[FM][FN];
#pragma unroll
  for (int i = 0; i < FM; i++)
#pragma unroll
    for (int j = 0; j < FN; j++) acc[i][j] = (f32x4){0.f, 0.f, 0.f, 0.f};

  const int frow = lane & 15;
  const int cgrp = lane >> 4;

  uint4 pa0, pa1, pa2, pa3;
  float4 pb0a, pb0b, pb1a, pb1b, pb2a, pb2b, pb3a, pb3b;
  int k0n = kbeg;
  LDA4(0, pa0); LDA4(1, pa1); LDA4(2, pa2); LDA4(3, pa3);
  LDB4(0, pb0a, pb0b); LDB4(1, pb1a, pb1b); LDB4(2, pb2a, pb2b); LDB4(3, pb3a, pb3b);

  for (int k0 = kbeg; k0 < kend; k0 += BK) {
    STA4(0, pa0); STA4(1, pa1); STA4(2, pa2); STA4(3, pa3);
    STB4(0, pb0a, pb0b); STB4(1, pb1a, pb1b); STB4(2, pb2a, pb2b); STB4(3, pb3a, pb3b);
    __syncthreads();
    if (k0 + BK < kend) {                     // prefetch next tile into named registers
      k0n = k0 + BK;
      LDA4(0, pa0); LDA4(1, pa1); LDA4(2, pa2); LDA4(3, pa3);
      LDB4(0, pb0a, pb0b); LDB4(1, pb1a, pb1b); LDB4(2, pb2a, pb2b); LDB4(3, pb3a, pb3b);
    }
#pragma unroll
    for (int kk = 0; kk < BK; kk += 32) {
      bf16x8 af[FM], bfr[FN];
#pragma unroll
      for (int i = 0; i < FM; i++) {
        int rr = wm + i * 16 + frow;
        int ch = (kk >> 3) + cgrp;
        af[i] = *reinterpret_cast<const bf16x8*>(&As[rr * BK + ((ch ^ (rr & (GPB - 1))) << 3)]);
      }
#pragma unroll
      for (int j = 0; j < FN; j++) {
        int rr = wn + j * 16 + frow;
        int ch = (kk >> 3) + cgrp;
        bfr[j] = *reinterpret_cast<const bf16x8*>(&Bs[rr * BK + ((ch ^ (rr & (GPB - 1))) << 3)]);
      }
#pragma unroll
      for (int i = 0; i < FM; i++)
#pragma unroll
        for (int j = 0; j < FN; j++)
          acc[i][j] = __builtin_amdgcn_mfma_f32_16x16x32_bf16(af[i], bfr[j], acc[i][j], 0, 0, 0);
    }
    __syncthreads();
  }

  const int crow = (lane >> 4) * 4;
  const int ccol = lane & 15;
  float* Cz = C + (size_t)z * TOKENS * N;
#pragma unroll
  for (int i = 0; i < FM; i++)
#pragma unroll
    for (int j = 0; j < FN; j++) {
      int row = m0 + wm + i * 16 + crow;
      int col = n0 + wn + j * 16 + ccol;
#pragma unroll
      for (int r = 0; r < 4; r++)
        Cz[(size_t)(row + r) * N + col] = acc[i][j][r];
    }
}

// ---------- fused attention: QK^T + softmax + PV + KAN-expand (pre-summed qkv) ----------

__global__ void attn_fused(const float* __restrict__ qkv, u16* __restrict__ Xe) {
  int bh = blockIdx.x, b = bh >> 2, h = bh & 3;
  int s0 = blockIdx.y * 16;
  int t = threadIdx.x;
  __shared__ float Qs[16][64];
  __shared__ float Ks[16][65];
  __shared__ float Ss[16][513];
  __shared__ float red[16][17];
  __shared__ float Vs[32][65];
#pragma unroll
  for (int c = 0; c < 4; c++) {
    int e = c * 256 + t, r = e >> 6, d = e & 63;
    Qs[r][d] = qkv[(size_t)(b * SEQ + s0 + r) * 768 + h * 64 + d];
  }
  int r = t >> 4, cc = t & 15;
  for (int kc = 0; kc < SEQ; kc += 16) {
    __syncthreads();
#pragma unroll
    for (int c = 0; c < 4; c++) {
      int e = c * 256 + t, rr = e >> 6, d = e & 63;
      Ks[rr][d] = qkv[(size_t)(b * SEQ + kc + rr) * 768 + 256 + h * 64 + d];
    }
    __syncthreads();
    float acc = 0.f;
#pragma unroll
    for (int d = 0; d < 64; d++) acc += Qs[r][d] * Ks[cc][d];
    Ss[r][kc + cc] = acc * 0.125f;
  }
  __syncthreads();
  float mx = -3.4e38f;
  for (int j = cc; j < SEQ; j += 16) mx = fmaxf(mx, Ss[r][j]);
  red[r][cc] = mx;
  __syncthreads();
  if (cc == 0) {
    float m = red[r][0];
#pragma unroll
    for (int j = 1; j < 16; j++) m = fmaxf(m, red[r][j]);
    red[r][16] = m;
  }
  __syncthreads();
  mx = red[r][16];
  float sm = 0.f;
  for (int j = cc; j < SEQ; j += 16) {
    float e = expf(Ss[r][j] - mx);
    Ss[r][j] = e;
    sm += e;
  }
  __syncthreads();
  red[r][cc] = sm;
  __syncthreads();
  if (cc == 0) {
    float s = 0.f;
#pragma unroll
    for (int j = 0; j < 16; j++) s += red[r][j];
    red[r][16] = s;
  }
  __syncthreads();
  float inv = 1.0f / red[r][16];
  for (int j = cc; j < SEQ; j += 16) Ss[r][j] *= inv;
  // PV
  int dd = cc * 4;
  float a0 = 0.f, a1 = 0.f, a2 = 0.f, a3 = 0.f;
  for (int kc = 0; kc < SEQ; kc += 32) {
    __syncthreads();
#pragma unroll
    for (int c = 0; c < 8; c++) {
      int e = c * 256 + t, rr = e >> 6, d = e & 63;
      Vs[rr][d] = qkv[(size_t)(b * SEQ + kc + rr) * 768 + 512 + h * 64 + d];
    }
    __syncthreads();
#pragma unroll
    for (int kk = 0; kk < 32; kk++) {
      float p = Ss[r][kc + kk];
      a0 += p * Vs[kk][dd + 0];
      a1 += p * Vs[kk][dd + 1];
      a2 += p * Vs[kk][dd + 2];
      a3 += p * Vs[kk][dd + 3];
    }
  }
  int row = b * SEQ + s0 + r;
  size_t base = (size_t)row * 2304;
  float av[4] = {a0, a1, a2, a3};
#pragma unroll
  for (int j = 0; j < 4; j++) {
    int col = h * 64 + dd + j;
    u16 s; us8 u;
    expand9(av[j], &s, &u);
    Xe[base + col] = s;
    *(us8*)(Xe + base + 256 + (size_t)col * 8) = u;
  }
}

// ---------- launch ----------

extern "C" void kernel_launch(void* const* d_in, const int* in_sizes, int n_in,
                              void* d_out, int out_size, void* d_ws, size_t ws_size,
                              hipStream_t stream) {
  const int* ids = (const int*)d_in[0];
  const float* wemb = (const float*)d_in[1];
  const float* ttemb = (const float*)d_in[2];
  const float* pemb = (const float*)d_in[3];
  const float* elg = (const float*)d_in[4];
  const float* elb = (const float*)d_in[5];
  const float* qb = (const float*)d_in[6], *qs = (const float*)d_in[7];
  const float* kb = (const float*)d_in[8], *ks = (const float*)d_in[9];
  const float* vb = (const float*)d_in[10], *vs = (const float*)d_in[11];
  const float* ob = (const float*)d_in[12], *osp = (const float*)d_in[13];
  const float* f1b = (const float*)d_in[14], *f1s = (const float*)d_in[15];
  const float* f2b = (const float*)d_in[16], *f2s = (const float*)d_in[17];
  const float* l1g = (const float*)d_in[18], *l1b = (const float*)d_in[19];
  const float* l2g = (const float*)d_in[20], *l2b = (const float*)d_in[21];
  const float* hkb = (const float*)d_in[22], *hks = (const float*)d_in[23];
  const float* hob = (const float*)d_in[24], *hos = (const float*)d_in[25];
  float* out = (float*)d_out;

  char* w = (char*)d_ws;
  const size_t MB = 1 << 20;
  float* xbuf  = (float*)(w);                 // 1 MB  [1024*256]
  float* tmp   = (float*)(w + 1 * MB);        // 1 MB  (head LN scratch)
  float* qkvp  = (float*)(w + 2 * MB);        // 18 MB [6][1024*768] split-K partials
  float* qkvs  = (float*)(w + 20 * MB);       // 3 MB  [1024*768]    summed
  float* part  = (float*)(w + 23 * MB);       // 12 MB [12][1024*256] split-K partials
  float* ff1p  = (float*)(w + 35 * MB);       // 24 MB [6][1024*1024] f1 partials
  u16*   Xe2   = (u16*)  (w + 59 * MB);       // 18 MB [1024*9216]   f1-out expansion
  u16*   Xe    = (u16*)  (w + 77 * MB);       // 4.5MB [1024*2304]

  embed_ln_x<<<TOKENS, 256, 0, stream>>>(ids, wemb, ttemb, pemb, elg, elb, xbuf, Xe);

  for (int l = 0; l < 4; l++) {
    const float* qbl = qb + (size_t)l * 65536, *qsl = qs + (size_t)l * 524288;
    const float* kbl = kb + (size_t)l * 65536, *ksl = ks + (size_t)l * 524288;
    const float* vbl = vb + (size_t)l * 65536, *vsl = vs + (size_t)l * 524288;
    const float* obl = ob + (size_t)l * 65536, *osl = osp + (size_t)l * 524288;
    const float* f1bl = f1b + (size_t)l * 262144, *f1sl = f1s + (size_t)l * 2097152;
    const float* f2bl = f2b + (size_t)l * 262144, *f2sl = f2s + (size_t)l * 2097152;

    // qkv: split-K x6 (1152 blocks, 3 iters/slice), then sum partials
    gemm_kw<64, 64, 128, 2><<<dim3(16, 12, 6), 256, 0, stream>>>(
        Xe, qbl, qsl, kbl, ksl, vbl, vsl, 256, 768, 2304, 256, 384, qkvp);
    qkv_sum<<<768, 256, 0, stream>>>(qkvp, qkvs, 6);
    attn_fused<<<dim3(8, 32), 256, 0, stream>>>(qkvs, Xe);
    // o-proj: split-K x9 (576 blocks, 2 iters/slice)
    gemm_kw<64, 64, 128, 2><<<dim3(16, 4, 9), 256, 0, stream>>>(
        Xe, obl, osl, obl, osl, obl, osl, 256, 256, 2304, 256, 256, part);
    add_ln_x<<<TOKENS, 256, 0, stream>>>(part, 9, TOKENS * 256, xbuf,
                                         l1g + l * 256, l1b + l * 256, 1e-5f, 0, xbuf, Xe);
    // f1: split-K x6 (1536 blocks, 3 iters/slice); expand_ff sums+relu+expands
    gemm_kw<64, 64, 128, 2><<<dim3(16, 16, 6), 256, 0, stream>>>(
        Xe, f1bl, f1sl, f1bl, f1sl, f1bl, f1sl, 1024, 1024, 2304, 256, 384, ff1p);
    expand_ff<<<4096, 256, 0, stream>>>(ff1p, Xe2, 6);
    // f2: split-K x12 (768 blocks, 6 iters/slice)
    gemm_kw<64, 64, 128, 2><<<dim3(16, 4, 12), 256, 0, stream>>>(
        Xe2, f2bl, f2sl, f2bl, f2sl, f2bl, f2sl, 256, 256, 9216, 1024, 768, part);
    add_ln_x<<<TOKENS, 256, 0, stream>>>(part, 12, TOKENS * 256, xbuf,
                                         l2g + l * 256, l2b + l * 256, 1e-5f, 0, xbuf, Xe);
  }

  // head: KAN -> gelu -> LN(no affine, eps 1e-12) -> KAN to vocab
  gemm_kw<64, 64, 128, 2><<<dim3(16, 4, 9), 256, 0, stream>>>(
      Xe, hkb, hks, hkb, hks, hkb, hks, 256, 256, 2304, 256, 256, part);
  add_ln_x<<<TOKENS, 256, 0, stream>>>(part, 9, TOKENS * 256, nullptr, nullptr, nullptr,
                                       1e-12f, 1, tmp, Xe);
  gemm_kw<128, 128, 64, 1><<<dim3(8, 250), 256, 0, stream>>>(
      Xe, hob, hos, hob, hos, hob, hos, 32000, 32000, 2304, 256, 2304, out);
}